// Round 1
// 1178.570 us; speedup vs baseline: 1.2407x; 1.2407x over previous
//
#include <hip/hip_runtime.h>
#include <stdint.h>
#include <stddef.h>

// Problem constants (QuantizedLinear: y = x @ (q*scale)^T)
#define M_DIM 8192   // 4*2048 rows of x
#define N_DIM 11008  // output channels
#define K_DIM 4096   // in features

typedef __attribute__((ext_vector_type(8))) __bf16 bf16x8;
typedef __attribute__((ext_vector_type(4))) float f32x4;

typedef const __attribute__((address_space(1))) void gvoid;
typedef __attribute__((address_space(3))) void lvoid;

__device__ __forceinline__ void async16(const void* g, void* l) {
  // global -> LDS direct copy, 16B/lane; LDS dest is wave-uniform base + lane*16
  __builtin_amdgcn_global_load_lds((gvoid*)g, (lvoid*)l, 16, 0, 0);
}

// round-to-nearest-even f32 -> bf16 (inputs are finite)
__device__ __forceinline__ unsigned short f2bf(float f) {
  unsigned u = __float_as_uint(f);
  u += 0x7fffu + ((u >> 16) & 1u);
  return (unsigned short)(u >> 16);
}

// ---------------- conversion passes (memory-bound, unchanged) ----------------

__global__ __launch_bounds__(256) void cvt_x_kernel(const float* __restrict__ x,
                                                    unsigned short* __restrict__ xw) {
  size_t i = ((size_t)blockIdx.x * 256 + threadIdx.x) * 4;
  float4 v = *(const float4*)(x + i);
  ushort4 o;
  o.x = f2bf(v.x); o.y = f2bf(v.y); o.z = f2bf(v.z); o.w = f2bf(v.w);
  *(ushort4*)(xw + i) = o;
}

__global__ __launch_bounds__(256) void cvt_w_kernel(const int* __restrict__ wq,
                                                    unsigned short* __restrict__ ww) {
  size_t i = ((size_t)blockIdx.x * 256 + threadIdx.x) * 4;
  int4 v = *(const int4*)(wq + i);
  ushort4 o;  // int values in [0,127) are exact in bf16
  o.x = f2bf((float)v.x); o.y = f2bf((float)v.y);
  o.z = f2bf((float)v.z); o.w = f2bf((float)v.w);
  *(ushort4*)(ww + i) = o;
}

// ---------------- main GEMM: 256x256 tile, BK=64, 8-phase counted-vmcnt ----------------
// A = x (M x K, K-contig), B = W (N x K, K-contig)  ->  C[m][n] = scale[n]*sum_k A*B
//
// 8 waves (2M x 4N), per-wave 128x64 output, 8x4 grid of 16x16x32 MFMAs.
// LDS 128 KiB: A-even [0,16384) shorts, A-odd [16384,32768), B-even [32768,49152),
// B-odd [49152,65536). Even K-tiles always in the *-even buffers (tile parity = buffer).
// T2 swizzle: 16B chunk index c ^= (row&7); applied on the global SOURCE address of
// global_load_lds (dest stays linear, rule #21) and undone on the ds_read address.
// T3+T4: per iteration (2 K-tiles) 8 phases, each {ds_reads; 2x global_load_lds;
// barrier; lgkmcnt(0); setprio(1); 16 MFMA; setprio(0); barrier}; s_waitcnt vmcnt(4)
// only at the two tile boundaries (phases 3 and 7) - never 0 in the loop.
//
// Stage map per iteration i (t = 2i):  ph0/1: B(t+1)h0,h1 -> B-odd
//   ph2: B(t+2)h0 -> B-even   ph3: A(t+2)h0 -> A-even   ph4: A(t+2)h1 -> A-even
//   ph5: B(t+2)h1 -> B-even   ph6: A(t+3)h0 -> A-odd    ph7: A(t+3)h1 -> A-odd
// Liveness: every region has >=1 full phase between last ds_read and overwrite
// landing, except ph6 (same-phase, reads issued before stage issue; ~200cy L2
// landing vs <150cy read service = positive margin; sched_barrier pins the order).

#define PH_MID                                            \
  __builtin_amdgcn_sched_barrier(0);                      \
  __builtin_amdgcn_s_barrier();                           \
  asm volatile("s_waitcnt lgkmcnt(0)" ::: "memory");      \
  __builtin_amdgcn_sched_barrier(0);                      \
  __builtin_amdgcn_s_setprio(1)

#define PH_END                                            \
  __builtin_amdgcn_s_setprio(0);                          \
  __builtin_amdgcn_sched_barrier(0);                      \
  __builtin_amdgcn_s_barrier()

#define PH_END_VM                                         \
  __builtin_amdgcn_s_setprio(0);                          \
  asm volatile("s_waitcnt vmcnt(4)" ::: "memory");        \
  __builtin_amdgcn_sched_barrier(0);                      \
  __builtin_amdgcn_s_barrier()

#define LD8(p, off) (*(const bf16x8*)((p) + (off)))

#define RD_A(PA0, PA1, IOFF)                                   \
  _Pragma("unroll") for (int ii = 0; ii < 4; ii++) {           \
    aR[ii][0] = LD8(PA0, ((IOFF) + ii) * 1024);                \
    aR[ii][1] = LD8(PA1, ((IOFF) + ii) * 1024);                \
  }

#define RD_B(BR, PB0, PB1, JOFF)                               \
  _Pragma("unroll") for (int jj = 0; jj < 2; jj++) {           \
    BR[jj][0] = LD8(PB0, ((JOFF) + jj) * 1024);                \
    BR[jj][1] = LD8(PB1, ((JOFF) + jj) * 1024);                \
  }

#define MFQ(IB, JB, BR)                                                         \
  _Pragma("unroll") for (int ii = 0; ii < 4; ii++)                              \
  _Pragma("unroll") for (int jj = 0; jj < 2; jj++)                              \
  _Pragma("unroll") for (int ss = 0; ss < 2; ss++)                              \
    acc[(IB) + ii][(JB) + jj] = __builtin_amdgcn_mfma_f32_16x16x32_bf16(        \
        aR[ii][ss], BR[jj][ss], acc[(IB) + ii][(JB) + jj], 0, 0, 0)

// stage one 64-row slab: wave v writes rows h*128+u*64+v*8 .. +7 (linear dest)
#define STG(g, s, h, u, kk)                                                     \
  async16((g) + (size_t)((h) * 128 + (u) * 64) * K_DIM + (kk),                  \
          (s) + ((h) * 128 + (u) * 64) * 64)

__global__ __launch_bounds__(512, 2) void gemm8(const unsigned short* __restrict__ xw,
                                                const unsigned short* __restrict__ ww,
                                                const float* __restrict__ scale,
                                                float* __restrict__ out) {
  extern __shared__ unsigned short smem[];  // 65536 shorts = 128 KiB

  const int tid = threadIdx.x;
  const int v = tid >> 6;   // wave 0..7
  const int l = tid & 63;
  const int wm = v >> 2, wn = v & 3;
  const int fm = l & 15, q = l >> 4;

  // T1: XCD-aware bijective swizzle; 1376 = 8*172 blocks; m-fast within an XCD
  // so consecutive co-resident blocks share the 2MB B-panel (L2-resident).
  const int flat = blockIdx.x;
  const int swz = (flat & 7) * 172 + (flat >> 3);
  const int m0 = (swz & 31) * 256;   // 32 M-tiles
  const int n0 = (swz >> 5) * 256;   // 43 N-tiles

  // staging lane geometry: row-in-slab sr = l>>3, swizzled source chunk
  const int sr = l >> 3;
  const int scn = (l & 7) ^ sr;  // LDS chunk (l&7) receives global chunk (l&7)^(row&7)
  const unsigned short* gA = xw + (size_t)(m0 + v * 8 + sr) * K_DIM + scn * 8;
  const unsigned short* gB = ww + (size_t)(n0 + v * 8 + sr) * K_DIM + scn * 8;
  unsigned short* const sA0 = smem + (v * 8) * 64;
  unsigned short* const sA1 = smem + 16384 + (v * 8) * 64;
  unsigned short* const sB0 = smem + 32768 + (v * 8) * 64;
  unsigned short* const sB1 = smem + 49152 + (v * 8) * 64;

  // frag-read bases; read of global chunk c at row r uses LDS chunk c^(r&7), r&7==fm&7
  const int ca = q ^ (fm & 7);                  // chunk for k-step s=0; s=1 is ca^4
  const unsigned short* const pA0 = smem + (wm * 128 + fm) * 64 + ca * 8;
  const unsigned short* const pA1 = smem + (wm * 128 + fm) * 64 + (ca ^ 4) * 8;
  const unsigned short* const pB0 = smem + 32768 + (wn * 64 + fm) * 64 + ca * 8;
  const unsigned short* const pB1 = smem + 32768 + (wn * 64 + fm) * 64 + (ca ^ 4) * 8;
  const unsigned short* const pA0o = pA0 + 16384;
  const unsigned short* const pA1o = pA1 + 16384;
  const unsigned short* const pB0o = pB0 + 16384;
  const unsigned short* const pB1o = pB1 + 16384;

  f32x4 acc[8][4];
#pragma unroll
  for (int i = 0; i < 8; i++)
#pragma unroll
    for (int j = 0; j < 4; j++) acc[i][j] = {0.f, 0.f, 0.f, 0.f};

  bf16x8 aR[4][2], b0R[2][2], b1R[2][2];

  // prologue: A(0)->A-even, B(0)->B-even, A(1)->A-odd (12 issues);
  // vmcnt(4) leaves A(1)'s 4 loads in flight, guarantees tile 0 landed.
  STG(gA, sA0, 0, 0, 0); STG(gA, sA0, 0, 1, 0);
  STG(gA, sA0, 1, 0, 0); STG(gA, sA0, 1, 1, 0);
  STG(gB, sB0, 0, 0, 0); STG(gB, sB0, 0, 1, 0);
  STG(gB, sB0, 1, 0, 0); STG(gB, sB0, 1, 1, 0);
  STG(gA, sA1, 0, 0, 64); STG(gA, sA1, 0, 1, 64);
  STG(gA, sA1, 1, 0, 64); STG(gA, sA1, 1, 1, 64);
  asm volatile("s_waitcnt vmcnt(4)" ::: "memory");
  __builtin_amdgcn_sched_barrier(0);
  __builtin_amdgcn_s_barrier();

  for (int it2 = 0; it2 < K_DIM / 128; ++it2) {
    const int ka = it2 * 128;
    const int k1 = ka + 64;
    int k2 = ka + 128; if (k2 > K_DIM - 64) k2 = K_DIM - 64;  // tail: harmless re-stage
    int k3 = ka + 192; if (k3 > K_DIM - 64) k3 = K_DIM - 64;

    // ph0: quadrant (mh0,nh0) of tile t; stage B(t+1,h0)
    RD_A(pA0, pA1, 0);
    RD_B(b0R, pB0, pB1, 0);
    STG(gB, sB1, 0, 0, k1); STG(gB, sB1, 0, 1, k1);
    PH_MID; MFQ(0, 0, b0R); PH_END;

    // ph1: (mh0,nh1); stage B(t+1,h1)
    RD_B(b1R, pB0, pB1, 2);
    STG(gB, sB1, 1, 0, k1); STG(gB, sB1, 1, 1, k1);
    PH_MID; MFQ(0, 2, b1R); PH_END;

    // ph2: (mh1,nh0) - aR reloaded with mh1; stage B(t+2,h0)
    RD_A(pA0, pA1, 4);
    STG(gB, sB0, 0, 0, k2); STG(gB, sB0, 0, 1, k2);
    PH_MID; MFQ(4, 0, b0R); PH_END;

    // ph3: (mh1,nh1); stage A(t+2,h0); tile boundary -> vmcnt(4)
    STG(gA, sA0, 0, 0, k2); STG(gA, sA0, 0, 1, k2);
    PH_MID; MFQ(4, 2, b1R); PH_END_VM;

    // ph4: tile t+1 (odd buffers), (mh0,nh0); stage A(t+2,h1)
    RD_A(pA0o, pA1o, 0);
    RD_B(b0R, pB0o, pB1o, 0);
    STG(gA, sA0, 1, 0, k2); STG(gA, sA0, 1, 1, k2);
    PH_MID; MFQ(0, 0, b0R); PH_END;

    // ph5: (mh0,nh1); stage B(t+2,h1)
    RD_B(b1R, pB0o, pB1o, 2);
    STG(gB, sB0, 1, 0, k2); STG(gB, sB0, 1, 1, k2);
    PH_MID; MFQ(0, 2, b1R); PH_END;

    // ph6: (mh1,nh0); stage A(t+3,h0) - same-phase/same-half case: pin reads first
    RD_A(pA0o, pA1o, 4);
    __builtin_amdgcn_sched_barrier(0);
    STG(gA, sA1, 0, 0, k3); STG(gA, sA1, 0, 1, k3);
    PH_MID; MFQ(4, 0, b0R); PH_END;

    // ph7: (mh1,nh1); stage A(t+3,h1); tile boundary -> vmcnt(4)
    STG(gA, sA1, 1, 0, k3); STG(gA, sA1, 1, 1, k3);
    PH_MID; MFQ(4, 2, b1R); PH_END_VM;
  }

  // epilogue: C/D layout col=lane&15, row=(lane>>4)*4+reg; fuse per-channel scale
  float sc4[4];
  const int baseN = n0 + wn * 64 + fm;
#pragma unroll
  for (int j = 0; j < 4; j++) sc4[j] = scale[baseN + j * 16];
#pragma unroll
  for (int i = 0; i < 8; i++) {
#pragma unroll
    for (int r = 0; r < 4; r++) {
      size_t row = (size_t)(m0 + wm * 128 + i * 16 + q * 4 + r);
      float* po = out + row * N_DIM + baseN;
#pragma unroll
      for (int j = 0; j < 4; j++) po[j * 16] = acc[i][j][r] * sc4[j];
    }
  }
}

// ---------------- fallback: fused conversion GEMM (no workspace), unchanged ----------------

__global__ __launch_bounds__(256) void gemm_fused(const float* __restrict__ x,
                                                  const int* __restrict__ wq,
                                                  const float* __restrict__ scale,
                                                  float* __restrict__ out) {
  __shared__ unsigned short As[128 * 32];
  __shared__ unsigned short Bs[128 * 32];

  const int tid = threadIdx.x;
  const int w = tid >> 6, l = tid & 63;
  const int n0 = blockIdx.x * 128;
  const int m0 = blockIdx.y * 128;

  const int srow = tid >> 2;
  const int scol = (tid & 3) * 8;

  const int wm = w >> 1, wn = w & 1;
  const int fm = l & 15, q = l >> 4;
  const unsigned short* pA = &As[(wm * 64 + fm) * 32 + q * 8];
  const unsigned short* pB = &Bs[(wn * 64 + fm) * 32 + q * 8];

  f32x4 acc[4][4];
#pragma unroll
  for (int i = 0; i < 4; i++)
#pragma unroll
    for (int j = 0; j < 4; j++) acc[i][j] = {0.f, 0.f, 0.f, 0.f};

  for (int kk = 0; kk < K_DIM; kk += 32) {
    __syncthreads();
#pragma unroll
    for (int h = 0; h < 2; h++) {
      int row = h * 64 + srow;
      const float* pa = x + (size_t)(m0 + row) * K_DIM + kk + scol;
      float4 a0 = *(const float4*)pa;
      float4 a1 = *(const float4*)(pa + 4);
      union { unsigned short us[8]; bf16x8 vv; } ua;
      ua.us[0] = f2bf(a0.x); ua.us[1] = f2bf(a0.y); ua.us[2] = f2bf(a0.z); ua.us[3] = f2bf(a0.w);
      ua.us[4] = f2bf(a1.x); ua.us[5] = f2bf(a1.y); ua.us[6] = f2bf(a1.z); ua.us[7] = f2bf(a1.w);
      *(bf16x8*)&As[row * 32 + scol] = ua.vv;

      const int* pb = wq + (size_t)(n0 + row) * K_DIM + kk + scol;
      int4 b0 = *(const int4*)pb;
      int4 b1 = *(const int4*)(pb + 4);
      union { unsigned short us[8]; bf16x8 vv; } ub;
      ub.us[0] = f2bf((float)b0.x); ub.us[1] = f2bf((float)b0.y);
      ub.us[2] = f2bf((float)b0.z); ub.us[3] = f2bf((float)b0.w);
      ub.us[4] = f2bf((float)b1.x); ub.us[5] = f2bf((float)b1.y);
      ub.us[6] = f2bf((float)b1.z); ub.us[7] = f2bf((float)b1.w);
      *(bf16x8*)&Bs[row * 32 + scol] = ub.vv;
    }
    __syncthreads();

    bf16x8 af[4], bf[4];
#pragma unroll
    for (int i = 0; i < 4; i++) af[i] = *(const bf16x8*)(pA + i * 16 * 32);
#pragma unroll
    for (int j = 0; j < 4; j++) bf[j] = *(const bf16x8*)(pB + j * 16 * 32);
#pragma unroll
    for (int i = 0; i < 4; i++)
#pragma unroll
      for (int j = 0; j < 4; j++)
        acc[i][j] = __builtin_amdgcn_mfma_f32_16x16x32_bf16(af[i], bf[j], acc[i][j], 0, 0, 0);
  }

  float sc[4];
  const int baseN = n0 + wn * 64 + fm;
#pragma unroll
  for (int j = 0; j < 4; j++) sc[j] = scale[baseN + j * 16];
#pragma unroll
  for (int i = 0; i < 4; i++) {
#pragma unroll
    for (int r = 0; r < 4; r++) {
      size_t row = (size_t)(m0 + wm * 64 + i * 16 + q * 4 + r);
      float* po = out + row * N_DIM + baseN;
#pragma unroll
      for (int j = 0; j < 4; j++) po[j * 16] = acc[i][j][r] * sc[j];
    }
  }
}

extern "C" void kernel_launch(void* const* d_in, const int* in_sizes, int n_in,
                              void* d_out, int out_size, void* d_ws, size_t ws_size,
                              hipStream_t stream) {
  const float* x = (const float*)d_in[0];
  const int* wq = (const int*)d_in[1];
  const float* sc = (const float*)d_in[2];
  float* out = (float*)d_out;

  const size_t xE = (size_t)M_DIM * K_DIM;  // 33,554,432
  const size_t wE = (size_t)N_DIM * K_DIM;  // 45,088,768
  const size_t need = (xE + wE) * sizeof(unsigned short);  // ~150 MB

  if (ws_size >= need) {
    static bool attr_set = false;
    if (!attr_set) {
      (void)hipFuncSetAttribute(reinterpret_cast<const void*>(gemm8),
                                hipFuncAttributeMaxDynamicSharedMemorySize, 131072);
      attr_set = true;
    }
    unsigned short* xw = (unsigned short*)d_ws;
    unsigned short* ww = xw + xE;
    cvt_x_kernel<<<(unsigned)(xE / 1024), 256, 0, stream>>>(x, xw);
    cvt_w_kernel<<<(unsigned)(wE / 1024), 256, 0, stream>>>(wq, ww);
    gemm8<<<dim3((M_DIM / 256) * (N_DIM / 256)), dim3(512), 131072, stream>>>(xw, ww, sc, out);
  } else {
    gemm_fused<<<dim3(N_DIM / 128, M_DIM / 128), 256, 0, stream>>>(x, wq, sc, out);
  }
}